// Round 4
// baseline (1256.861 us; speedup 1.0000x reference)
//
#include <hip/hip_runtime.h>
#include <hip/hip_bf16.h>

#define T_TOK 8192
#define NSLOT 16384
#define DM 512
#define DF 2048
#define NEXP 64
#define CAP 320
#define MP 384   // padded rows per expert (3 x 128 tiles)

typedef __bf16 bf16_t;
typedef __bf16 bf16x8 __attribute__((ext_vector_type(8)));
typedef float floatx4 __attribute__((ext_vector_type(4)));

__device__ __forceinline__ void lgkm0_barrier() {
    // lgkmcnt(0) only — vmcnt stays outstanding across the barrier (wave-private
    // VGPR loads need no cross-wave visibility). This is what keeps the 2-deep
    // register pipeline alive; __syncthreads() would drain vmcnt(0).
    asm volatile("s_waitcnt lgkmcnt(0)" ::: "memory");
    __builtin_amdgcn_s_barrier();
    asm volatile("" ::: "memory");
}

// ---------------- K1: scores -> expert ids (hash 0,1 only); also init inv = -1
__global__ __launch_bounds__(256) void k_scores(const float* __restrict__ x,
        const float* __restrict__ Wh, int* __restrict__ e_arr, int* __restrict__ inv)
{
    int tid = threadIdx.x;
    if (tid < 10) inv[blockIdx.x * 10 + tid] = -1;   // 2048*10 = 20480 = NEXP*CAP
    int wid = tid >> 6, lane = tid & 63;
    int t = blockIdx.x * 4 + wid;
    const float4* xp = (const float4*)(x + (size_t)t * DM);
    float4 x0 = xp[lane * 2], x1 = xp[lane * 2 + 1];
    const float4* w0p = (const float4*)(Wh);
    const float4* w1p = (const float4*)(Wh + DM);
    float4 a0 = w0p[lane * 2], a1 = w0p[lane * 2 + 1];
    float4 b0 = w1p[lane * 2], b1 = w1p[lane * 2 + 1];
    float s0 = x0.x*a0.x + x0.y*a0.y + x0.z*a0.z + x0.w*a0.w
             + x1.x*a1.x + x1.y*a1.y + x1.z*a1.z + x1.w*a1.w;
    float s1 = x0.x*b0.x + x0.y*b0.y + x0.z*b0.z + x0.w*b0.w
             + x1.x*b1.x + x1.y*b1.y + x1.z*b1.z + x1.w*b1.w;
    #pragma unroll
    for (int off = 32; off; off >>= 1) {
        s0 += __shfl_xor(s0, off);
        s1 += __shfl_xor(s1, off);
    }
    if (lane == 0) {
        int q0 = ((int)floorf(s0 * 8.0f)) & 63;   // python mod 64 == &63
        int q1 = ((int)floorf(s1 * 8.0f)) & 63;
        e_arr[2 * t]     = q0;
        e_arr[2 * t + 1] = q1;
    }
}

// ---------------- K2: per-256-slot-chunk histogram + stable local rank
__global__ __launch_bounds__(256) void k_hist(const int* __restrict__ e_arr,
        int* __restrict__ rank_arr, int* __restrict__ hist_g)
{
    __shared__ int se[256];
    __shared__ int hist[64];
    int tid = threadIdx.x;
    if (tid < 64) hist[tid] = 0;
    __syncthreads();
    int s = blockIdx.x * 256 + tid;
    int e = e_arr[s];
    se[tid] = e;
    atomicAdd(&hist[e], 1);
    __syncthreads();
    int cnt = 0;
    for (int j = 0; j < 255; ++j)
        if (j < tid && se[j] == e) cnt++;
    rank_arr[s] = cnt;
    if (tid < 64) hist_g[blockIdx.x * 64 + tid] = hist[tid];
}

// ---------------- K3: one block per chunk; prefix over earlier chunks -> pos + inverse map
__global__ __launch_bounds__(256) void k_pos(const int* __restrict__ e_arr,
        const int* __restrict__ rank_arr, const int* __restrict__ hist_g,
        int* __restrict__ pos_arr, int* __restrict__ inv)
{
    __shared__ int base[64];
    int tid = threadIdx.x, c = blockIdx.x;
    if (tid < 64) {
        int run = 0;
        for (int cc = 0; cc < c; ++cc) run += hist_g[cc * 64 + tid];
        base[tid] = run;
    }
    __syncthreads();
    int s = c * 256 + tid;
    int e = e_arr[s];
    int p = base[e] + rank_arr[s];
    pos_arr[s] = p;
    if (p < CAP) inv[e * CAP + p] = s;
}

// ---------------- K4: build buf (bf16, MP rows/expert), zero unfilled/pad rows.
__global__ __launch_bounds__(256) void k_buf(const float* __restrict__ x,
        const int* __restrict__ inv, bf16_t* __restrict__ buf)
{
    int tid = threadIdx.x;
    int r = blockIdx.x * 4 + (tid >> 6);     // 0 .. 64*MP-1
    int lane = tid & 63;
    int e = r / MP, row = r % MP;
    int s = (row < CAP) ? inv[e * CAP + row] : -1;
    union { uint4 u; bf16_t h[8]; } pk;
    if (s >= 0) {
        int t = s >> 1;
        const float* xr = x + (size_t)t * DM + lane * 8;
        float4 f0 = *(const float4*)xr;
        float4 f1 = *(const float4*)(xr + 4);
        pk.h[0] = (bf16_t)f0.x; pk.h[1] = (bf16_t)f0.y;
        pk.h[2] = (bf16_t)f0.z; pk.h[3] = (bf16_t)f0.w;
        pk.h[4] = (bf16_t)f1.x; pk.h[5] = (bf16_t)f1.y;
        pk.h[6] = (bf16_t)f1.z; pk.h[7] = (bf16_t)f1.w;
    } else {
        pk.u.x = 0; pk.u.y = 0; pk.u.z = 0; pk.u.w = 0;
    }
    *(uint4*)(buf + (size_t)r * DM + lane * 8) = pk.u;
}

// ---------------- Pipelined GEMM: C[e] = act(A[e](bf16 [MP][K]) @ B[e](fp32 [K][N]) [+ bias])
// Double-buffered LDS, ONE raw barrier per K-iter (lgkmcnt-only), 2-deep VGPR
// prefetch (tiles t+1,t+2 staged; freed stage reloads t+3) -> global loads stay
// in flight across barriers. XOR-granule LDS swizzle (verified conflict-free).
// MFMA operands swapped: lane&15 = m, quad*4+r = n -> vector epilogue.
template<int M_TOT, int OSTR, int N_DIM, int K_DIM, bool GELU, bool BIAS, bool OUT_BF16>
__global__ __launch_bounds__(256, 2) void gemm_pipe(const bf16_t* __restrict__ A,
        const float* __restrict__ B, const float* __restrict__ bias,
        void* __restrict__ OutP)
{
    constexpr int NT = N_DIM / 128;
    constexpr int NTILE = K_DIM / 64;
    // grid: bx = g + (NEXP*NT)*mt, g = e*NT + nt. mt-blocks sharing a B-slab are
    // NEXP*NT apart (multiple of 8) -> same XCD for L2 reuse of W.
    int bx = blockIdx.x;
    int mt = bx / (NEXP * NT);
    int g  = bx % (NEXP * NT);
    int e  = g / NT;
    int nt = g % NT;

    const bf16_t* Ae = A + (size_t)e * MP * K_DIM + (size_t)mt * 128 * K_DIM;
    const float*  Be = B + (size_t)e * K_DIM * N_DIM + nt * 128;

    __shared__ __align__(16) bf16_t As[2][128 * 64];   // 16 KB each
    __shared__ __align__(16) bf16_t Bs[2][128 * 64];

    int tid = threadIdx.x;
    int lane = tid & 63;
    int wid = tid >> 6;
    int qm = lane & 15;
    int quad = lane >> 4;
    int wm = (wid >> 1) * 64;
    int wn = (wid & 1) * 64;

    // A staging: wave wid covers rows wid*32..+31; phys granule = row*8 + (g ^ (row&7))
    int srow = lane >> 3;
    int gl = (lane & 7) ^ srow;
    const bf16_t* aPtr = Ae + (size_t)(wid * 32 + srow) * K_DIM + gl * 8;
    // B staging: thread covers k-rows bkg*8..+7, n-cols bn..bn+3
    int bkg = tid & 7;
    int bn  = (tid >> 3) * 4;
    const float* bPtr = Be + (size_t)(bkg * 8) * N_DIM + bn;

    uint4  aS[2][4];
    float4 bS[2][8];

    #define LOAD_A(st, t_) { _Pragma("unroll") \
        for (int c = 0; c < 4; ++c) \
            aS[st][c] = *(const uint4*)(aPtr + (size_t)c * 8 * K_DIM + (t_) * 64); }
    #define LOAD_B(st, t_) { _Pragma("unroll") \
        for (int p = 0; p < 8; ++p) \
            bS[st][p] = *(const float4*)(bPtr + (size_t)((t_) * 64 + p) * N_DIM); }
    #define STAGE(lb, st) { \
        _Pragma("unroll") \
        for (int c = 0; c < 4; ++c) \
            *(uint4*)(&As[lb][((wid * 4 + c) * 64 + lane) * 8]) = aS[st][c]; \
        _Pragma("unroll") \
        for (int i = 0; i < 4; ++i) { \
            union { uint4 u; bf16_t h[8]; } pk; \
            _Pragma("unroll") \
            for (int p = 0; p < 8; ++p) \
                pk.h[p] = (bf16_t)(((const float*)&bS[st][p])[i]); \
            int r_ = bn + i; \
            *(uint4*)(&Bs[lb][(r_ * 8 + (bkg ^ (r_ & 7))) * 8]) = pk.u; \
        } }

    floatx4 acc[4][4];
    #pragma unroll
    for (int i = 0; i < 4; ++i)
        #pragma unroll
        for (int j = 0; j < 4; ++j) acc[i][j] = (floatx4)0.0f;

    // prologue: LDS[0] <- tile0 ; stages hold tile1 (S1), tile2 (S0)
    LOAD_A(0, 0); LOAD_B(0, 0);
    STAGE(0, 0);
    if (NTILE > 1) { LOAD_A(1, 1); LOAD_B(1, 1); }
    if (NTILE > 2) { LOAD_A(0, 2); LOAD_B(0, 2); }
    lgkm0_barrier();

    for (int t = 0; t < NTILE; ++t) {
        int cur = t & 1;
        if (t + 1 < NTILE) {
            int s = (t + 1) & 1;
            STAGE(cur ^ 1, s);                       // tile t+1 -> other LDS half
            if (t + 3 < NTILE) { LOAD_A(s, t + 3); LOAD_B(s, t + 3); }
        }
        #pragma unroll
        for (int ks = 0; ks < 2; ++ks) {
            bf16x8 af[4], bfr[4];
            #pragma unroll
            for (int i = 0; i < 4; ++i) {
                int r = wm + i * 16 + qm;
                int pg = r * 8 + ((ks * 4 + quad) ^ (r & 7));
                af[i] = *(const bf16x8*)(&As[cur][pg * 8]);
            }
            #pragma unroll
            for (int j = 0; j < 4; ++j) {
                int r = wn + j * 16 + qm;
                int pg = r * 8 + ((ks * 4 + quad) ^ (r & 7));
                bfr[j] = *(const bf16x8*)(&Bs[cur][pg * 8]);
            }
            #pragma unroll
            for (int i = 0; i < 4; ++i)
                #pragma unroll
                for (int j = 0; j < 4; ++j)
                    acc[i][j] = __builtin_amdgcn_mfma_f32_16x16x32_bf16(
                        bfr[j], af[i], acc[i][j], 0, 0, 0);   // swapped: C^T frag
        }
        lgkm0_barrier();
    }
    #undef LOAD_A
    #undef LOAD_B
    #undef STAGE

    // epilogue: lane holds m = wm+i*16+qm (uniform guard), n = wn+j*16+quad*4+r
    #pragma unroll
    for (int i = 0; i < 4; ++i) {
        int gm = mt * 128 + wm + i * 16 + qm;
        if (gm < M_TOT) {
            #pragma unroll
            for (int j = 0; j < 4; ++j) {
                int ln0 = wn + j * 16 + quad * 4;
                float v[4];
                #pragma unroll
                for (int r = 0; r < 4; ++r) v[r] = acc[i][j][r];
                if (BIAS) {
                    float4 bz = *(const float4*)(bias + (size_t)e * N_DIM + nt * 128 + ln0);
                    #pragma unroll
                    for (int r = 0; r < 4; ++r) v[r] += ((const float*)&bz)[r];
                }
                if (GELU) {
                    #pragma unroll
                    for (int r = 0; r < 4; ++r)
                        v[r] = 0.5f * v[r] * (1.0f + erff(v[r] * 0.70710678118654752f));
                }
                size_t idx = ((size_t)e * OSTR + gm) * N_DIM + nt * 128 + ln0;
                if (OUT_BF16) {
                    union { uint2 u; bf16_t h[4]; } pk;
                    pk.h[0] = (bf16_t)v[0]; pk.h[1] = (bf16_t)v[1];
                    pk.h[2] = (bf16_t)v[2]; pk.h[3] = (bf16_t)v[3];
                    *(uint2*)((bf16_t*)OutP + idx) = pk.u;
                } else {
                    float4 o; o.x = v[0]; o.y = v[1]; o.z = v[2]; o.w = v[3];
                    *(float4*)((float*)OutP + idx) = o;
                }
            }
        }
    }
}

// ---------------- K7: gather + mean over the two slots; fold b2 (per-expert) here
__global__ __launch_bounds__(256) void k_gather(const bf16_t* __restrict__ y,
        const float* __restrict__ b2, const int* __restrict__ e_arr,
        const int* __restrict__ pos_arr, float* __restrict__ out)
{
    int tid = threadIdx.x;
    int t = blockIdx.x * 4 + (tid >> 6);
    int lane = tid & 63;
    float a[8];
    #pragma unroll
    for (int i = 0; i < 8; ++i) a[i] = 0.0f;
    #pragma unroll
    for (int k = 0; k < 2; ++k) {
        int s = 2 * t + k;
        int e = e_arr[s], p = pos_arr[s];
        if (p < CAP) {
            union { uint4 u; bf16_t h[8]; } raw;
            raw.u = *(const uint4*)(y + ((size_t)e * CAP + p) * DM + lane * 8);
            const float* bz = b2 + (size_t)e * DM + lane * 8;
            float4 z0 = ((const float4*)bz)[0];
            float4 z1 = ((const float4*)bz)[1];
            a[0] += (float)raw.h[0] + z0.x; a[1] += (float)raw.h[1] + z0.y;
            a[2] += (float)raw.h[2] + z0.z; a[3] += (float)raw.h[3] + z0.w;
            a[4] += (float)raw.h[4] + z1.x; a[5] += (float)raw.h[5] + z1.y;
            a[6] += (float)raw.h[6] + z1.z; a[7] += (float)raw.h[7] + z1.w;
        }
    }
    float4 o0, o1;
    o0.x = a[0] * 0.5f; o0.y = a[1] * 0.5f; o0.z = a[2] * 0.5f; o0.w = a[3] * 0.5f;
    o1.x = a[4] * 0.5f; o1.y = a[5] * 0.5f; o1.z = a[6] * 0.5f; o1.w = a[7] * 0.5f;
    float* orow = out + (size_t)t * DM + lane * 8;
    *(float4*)orow = o0;
    *(float4*)(orow + 4) = o1;
}

extern "C" void kernel_launch(void* const* d_in, const int* in_sizes, int n_in,
                              void* d_out, int out_size, void* d_ws, size_t ws_size,
                              hipStream_t stream)
{
    const float* x  = (const float*)d_in[0];
    const float* Wh = (const float*)d_in[1];
    const float* W1 = (const float*)d_in[2];
    const float* b1 = (const float*)d_in[3];
    const float* W2 = (const float*)d_in[4];
    const float* b2 = (const float*)d_in[5];
    float* out = (float*)d_out;

    char* p = (char*)d_ws;
    int*    e_arr  = (int*)p;    p += (size_t)NSLOT * 4;
    int*    rank_a = (int*)p;    p += (size_t)NSLOT * 4;
    int*    hist_g = (int*)p;    p += (size_t)64 * 64 * 4;
    int*    pos_a  = (int*)p;    p += (size_t)NSLOT * 4;
    int*    inv    = (int*)p;    p += (size_t)NEXP * CAP * 4;
    // buf (bf16, 25.2MB) and ybuf (bf16, 21MB) overlap: buf dead before GEMM2 writes ybuf
    bf16_t* buf    = (bf16_t*)p;
    bf16_t* ybuf   = (bf16_t*)p; p += (size_t)NEXP * MP * DM * 2;
    bf16_t* hbuf   = (bf16_t*)p; p += (size_t)NEXP * MP * DF * 2;

    k_scores<<<2048, 256, 0, stream>>>(x, Wh, e_arr, inv);
    k_hist<<<64, 256, 0, stream>>>(e_arr, rank_a, hist_g);
    k_pos<<<64, 256, 0, stream>>>(e_arr, rank_a, hist_g, pos_a, inv);
    k_buf<<<NEXP * MP / 4, 256, 0, stream>>>(x, inv, buf);

    // GEMM1: buf[e][384][512] @ W1[e][512][2048] + b1 -> gelu -> hbuf (bf16)
    gemm_pipe<CAP, MP, DF, DM, true, true, true>
        <<<NEXP * 3 * (DF / 128), 256, 0, stream>>>(buf, W1, b1, (void*)hbuf);

    // GEMM2: hbuf[e][384][2048] @ W2[e][2048][512] -> ybuf (bf16, bias folded into gather)
    gemm_pipe<CAP, CAP, DM, DF, false, false, true>
        <<<NEXP * 3 * (DM / 128), 256, 0, stream>>>(hbuf, W2, nullptr, (void*)ybuf);

    k_gather<<<2048, 256, 0, stream>>>(ybuf, b2, e_arr, pos_a, out);
}